// Round 9
// baseline (36.511 us; speedup 1.0000x reference)
//
#include <hip/hip_runtime.h>
#include <math.h>

#define FF 20
#define TPB 256              // 4 waves per block
#define TPW 8                // tiles per wave, all loads issued up-front

typedef __fp16 half2v __attribute__((ext_vector_type(2)));
typedef __fp16 half8 __attribute__((ext_vector_type(8)));
typedef float f32x4 __attribute__((ext_vector_type(4)));

#define MFMA16(A, B, C) __builtin_amdgcn_mfma_f32_16x16x32_f16(A, B, C, 0, 0, 0)

// Per-tile body (macro, NOT a lambda/function: R5 showed pointer-param lambdas
// defeat SROA and send the batch to scratch).
// B1 = x-row fragment -> GEMM1 -> relu/pack (C/D row pattern == A/B k pattern,
// zero cross-lane) -> GEMM2 -> accumulate sum/|sum|.
#define TILE_BODY(XA, XB, LIVE)                                                \
    {                                                                          \
        half8 B1;                                                              \
        half2v p0 = __builtin_amdgcn_cvt_pkrtz((XA).x, (XA).y);                \
        half2v p1 = __builtin_amdgcn_cvt_pkrtz((XA).z, (XA).w);                \
        B1[0] = p0[0]; B1[1] = p0[1]; B1[2] = p1[0]; B1[3] = p1[1];            \
        if (g == 0) {                                                          \
            half2v p2 = __builtin_amdgcn_cvt_pkrtz((XB).x, (XB).y);            \
            half2v p3 = __builtin_amdgcn_cvt_pkrtz((XB).z, (XB).w);            \
            B1[4] = p2[0]; B1[5] = p2[1]; B1[6] = p3[0]; B1[7] = p3[1];        \
        } else if (g == 1) {                                                   \
            B1[4] = (__fp16)1.0f;  /* k==20 -> constant-1 bias column */       \
            B1[5] = (__fp16)0.f; B1[6] = (__fp16)0.f; B1[7] = (__fp16)0.f;     \
        } else {                                                               \
            B1[4] = (__fp16)0.f; B1[5] = (__fp16)0.f;                          \
            B1[6] = (__fp16)0.f; B1[7] = (__fp16)0.f;                          \
        }                                                                      \
        f32x4 c0 = MFMA16(A10, B1, zero);                                      \
        f32x4 c1 = MFMA16(A11, B1, zero);                                      \
        half8 B2;                                                              \
        half2v q0 = __builtin_amdgcn_cvt_pkrtz(fmaxf(c0[0],0.f), fmaxf(c0[1],0.f)); \
        half2v q1 = __builtin_amdgcn_cvt_pkrtz(fmaxf(c0[2],0.f), fmaxf(c0[3],0.f)); \
        half2v q2 = __builtin_amdgcn_cvt_pkrtz(fmaxf(c1[0],0.f), fmaxf(c1[1],0.f)); \
        half2v q3 = __builtin_amdgcn_cvt_pkrtz(fmaxf(c1[2],0.f), fmaxf(c1[3],0.f)); \
        B2[0] = q0[0]; B2[1] = q0[1]; B2[2] = q1[0]; B2[3] = q1[1];            \
        B2[4] = q2[0]; B2[5] = q2[1]; B2[6] = q3[0]; B2[7] = q3[1];            \
        if (g == 1) B2[4] = (__fp16)1.0f;  /* m==20 -> h2_ext bias row */      \
        f32x4 d0 = MFMA16(A20, B2, zero);                                      \
        f32x4 d1 = MFMA16(A21, B2, zero);                                      \
        if (LIVE) {                                                            \
            _Pragma("unroll")                                                  \
            for (int q = 0; q < 4; ++q) {                                      \
                psum += d0[q]; pabs += fabsf(d0[q]);                           \
                psum += d1[q]; pabs += fabsf(d1[q]);                           \
            }                                                                  \
        }                                                                      \
    }

// ---------------------------------------------------------------------------
// Fused-head main kernel (no setup kernel): every wave builds its four MFMA
// A-fragments itself. Key identity: At^T = W^T x R, and the MFMA C/D layout
// (row = 4g+q, col = l&15) is EXACTLY the A-operand per-lane k-pattern, so
// 4 MFMAs on f16 W^T/R fragments produce A10/A11 directly in-lane:
//   D00 = W^T(rows 0-15)  x R(cols 0-15)   -> A10 e=0..3
//   D10 = [W^T rows16-19; b^T] x R(cols 0-15) -> A10 e=4..7 (+1 at k==20)
//   D01/D11: same with R cols 16-19        -> A11
// A20/A21 (GEMM2 = W_ext rows, k=m) are direct gathers of W/b.
// Tail: block partial -> partials[] (separate final kernel; fused tails are
// codegen-toxic per R5-R7: 40-44 VGPR load-serialized 3x slowdown).
// ---------------------------------------------------------------------------
__global__ __launch_bounds__(TPB) void mlp_main(
    const float* __restrict__ x, const float* __restrict__ W,
    const float* __restrict__ bv, const float* __restrict__ R,
    double2* __restrict__ partials, int nrows)
{
    const int t = threadIdx.x;
    const int l = t & 63;
    const int g = l >> 4;        // 0..3 (k-chunk)
    const int r = l & 15;        // tile-row / fragment row-col index

    // ---- prelude: 48 L2-hot gathers + 4 MFMAs, once per wave ----
    half8 AW0, AP, BR0, BR1, A20, A21;
    #pragma unroll
    for (int e = 0; e < 8; ++e) {
        const int j = (e < 4) ? (4 * g + e) : (16 + 4 * g + (e - 4));
        const bool jv = (j < FF);
        float aw0 = jv ? W[j * FF + r] : 0.f;            // W^T[r][j]
        float ap = 0.f;                                   // rows 16..20 tile
        if (jv) {
            if (r < 4)       ap = W[j * FF + 16 + r];     // W^T[16+r][j]
            else if (r == 4) ap = bv[j];                  // bias row i==20
        }
        float br0 = jv ? R[j * FF + r] : 0.f;             // R[j][r]
        float br1 = (jv && r < 4) ? R[j * FF + 16 + r] : 0.f;
        float a20 = jv ? W[r * FF + j] : ((j == FF) ? bv[r] : 0.f);
        float a21 = 0.f;
        if (r < 4) a21 = jv ? W[(16 + r) * FF + j] : ((j == FF) ? bv[16 + r] : 0.f);
        AW0[e] = (__fp16)aw0; AP[e]  = (__fp16)ap;
        BR0[e] = (__fp16)br0; BR1[e] = (__fp16)br1;
        A20[e] = (__fp16)a20; A21[e] = (__fp16)a21;
    }
    const f32x4 zero = {0.f, 0.f, 0.f, 0.f};
    f32x4 D00 = MFMA16(AW0, BR0, zero);
    f32x4 D10 = MFMA16(AP,  BR0, zero);
    f32x4 D01 = MFMA16(AW0, BR1, zero);
    f32x4 D11 = MFMA16(AP,  BR1, zero);
    half8 A10, A11;
    A10[0] = (__fp16)D00[0]; A10[1] = (__fp16)D00[1];
    A10[2] = (__fp16)D00[2]; A10[3] = (__fp16)D00[3];
    A11[0] = (__fp16)D01[0]; A11[1] = (__fp16)D01[1];
    A11[2] = (__fp16)D01[2]; A11[3] = (__fp16)D01[3];
    {
        float v0 = D10[0], v1 = D11[0];
        if (g == 1) { v0 += 1.f; if (r < 4) v1 += 1.f; }  // c[m] = 1 + b.R (k==20)
        A10[4] = (__fp16)v0;      A11[4] = (__fp16)v1;
        A10[5] = (__fp16)D10[1];  A11[5] = (__fp16)D11[1];
        A10[6] = (__fp16)D10[2];  A11[6] = (__fp16)D11[2];
        A10[7] = (__fp16)D10[3];  A11[7] = (__fp16)D11[3];
    }

    // ---- main: one flat batch of TPW tiles, all loads issued up-front ----
    const int wave_id = blockIdx.x * (TPB / 64) + (t >> 6);
    const long base_row = (long)wave_id * (TPW * 16) + r;
    const float* rowp = x + base_row * FF;
    float psum = 0.f, pabs = 0.f;
    float4 xa[TPW], xb[TPW];
    const bool full = ((long)(wave_id + 1) * (TPW * 16)) <= (long)nrows;

    if (full) {
        #pragma unroll
        for (int u = 0; u < TPW; ++u)
            xa[u] = *reinterpret_cast<const float4*>(rowp + (size_t)u * 16 * FF + 4 * g);
        #pragma unroll
        for (int u = 0; u < TPW; ++u) {
            xb[u] = make_float4(0.f, 0.f, 0.f, 0.f);
            if (g == 0)
                xb[u] = *reinterpret_cast<const float4*>(rowp + (size_t)u * 16 * FF + 16);
        }
        #pragma unroll
        for (int u = 0; u < TPW; ++u)
            TILE_BODY(xa[u], xb[u], true);
    } else {
        #pragma unroll
        for (int u = 0; u < TPW; ++u) {
            long row = base_row + u * 16;
            xa[u] = make_float4(0.f, 0.f, 0.f, 0.f);
            xb[u] = make_float4(0.f, 0.f, 0.f, 0.f);
            if (row < nrows) {
                xa[u] = *reinterpret_cast<const float4*>(rowp + (size_t)u * 16 * FF + 4 * g);
                if (g == 0)
                    xb[u] = *reinterpret_cast<const float4*>(rowp + (size_t)u * 16 * FF + 16);
            }
        }
        #pragma unroll
        for (int u = 0; u < TPW; ++u)
            TILE_BODY(xa[u], xb[u], (base_row + u * 16 < nrows));
    }

    // ---- wave + block reduction -> one double2 per block ----
    #pragma unroll
    for (int off = 32; off > 0; off >>= 1) {
        psum += __shfl_down(psum, off, 64);
        pabs += __shfl_down(pabs, off, 64);
    }
    __shared__ double wsum[TPB / 64], wabs[TPB / 64];
    if ((t & 63) == 0) { wsum[t >> 6] = (double)psum; wabs[t >> 6] = (double)pabs; }
    __syncthreads();
    if (t == 0) {
        double bs = 0.0, ba = 0.0;
        #pragma unroll
        for (int w = 0; w < TPB / 64; ++w) { bs += wsum[w]; ba += wabs[w]; }
        partials[blockIdx.x] = make_double2(bs, ba);
    }
}

// ---------------------------------------------------------------------------
// Final: deterministic tree-reduce of block partials; halving count; output.
// ---------------------------------------------------------------------------
__global__ __launch_bounds__(256) void mlp_final(const double2* __restrict__ parts,
                                                 int nparts, float* __restrict__ out) {
    __shared__ double s_sum[256], s_abs[256];
    int t = threadIdx.x;
    double a = 0.0, sg = 0.0;
    for (int i = t; i < nparts; i += 256) { sg += parts[i].x; a += parts[i].y; }
    s_sum[t] = sg; s_abs[t] = a;
    __syncthreads();
    for (int off = 128; off > 0; off >>= 1) {
        if (t < off) { s_sum[t] += s_sum[t + off]; s_abs[t] += s_abs[t + off]; }
        __syncthreads();
    }
    if (t == 0) {
        double s = s_abs[0];
        int k = 0;
        while (s > 1.0 && k < 4000) { s *= 0.5; ++k; }
        out[0] = (float)ldexp(s_sum[0], -k);
    }
}

extern "C" void kernel_launch(void* const* d_in, const int* in_sizes, int n_in,
                              void* d_out, int out_size, void* d_ws, size_t ws_size,
                              hipStream_t stream) {
    const float* x = (const float*)d_in[0];
    const float* W = (const float*)d_in[1];
    const float* bv = (const float*)d_in[2];
    const float* R = (const float*)d_in[3];
    float* out = (float*)d_out;

    double2* partials = (double2*)d_ws;

    int nrows = in_sizes[0] / FF;
    int ntiles = (nrows + 15) / 16;
    int waves = (ntiles + TPW - 1) / TPW;
    int blocks = (waves + (TPB / 64) - 1) / (TPB / 64);

    hipLaunchKernelGGL(mlp_main, dim3(blocks), dim3(TPB), 0, stream,
                       x, W, bv, R, partials, nrows);
    hipLaunchKernelGGL(mlp_final, dim3(1), dim3(256), 0, stream, partials, blocks, out);
}

// Round 10
// 30.866 us; speedup vs baseline: 1.1829x; 1.1829x over previous
//
#include <hip/hip_runtime.h>
#include <math.h>

#define FF 20
#define TPB 256              // 4 waves per block
#define TPW 8                // tiles per wave
#define TILE_BYTES (16 * FF * 4)          // 1280 B per 16-row tile
#define WAVE_BYTES (TPW * TILE_BYTES)     // 10240 B per wave
#define DMA_N (WAVE_BYTES / 1024)         // 10 dense global_load_lds per wave

typedef __fp16 half2v __attribute__((ext_vector_type(2)));
typedef __fp16 half8 __attribute__((ext_vector_type(8)));
typedef float f32x4 __attribute__((ext_vector_type(4)));

#define MFMA16(A, B, C) __builtin_amdgcn_mfma_f32_16x16x32_f16(A, B, C, 0, 0, 0)

// Per-tile body (macro, not lambda: R5 showed lambdas defeat SROA).
#define TILE_BODY(XA, XB, LIVE)                                                \
    {                                                                          \
        half8 B1;                                                              \
        half2v p0 = __builtin_amdgcn_cvt_pkrtz((XA).x, (XA).y);                \
        half2v p1 = __builtin_amdgcn_cvt_pkrtz((XA).z, (XA).w);                \
        B1[0] = p0[0]; B1[1] = p0[1]; B1[2] = p1[0]; B1[3] = p1[1];            \
        if (g == 0) {                                                          \
            half2v p2 = __builtin_amdgcn_cvt_pkrtz((XB).x, (XB).y);            \
            half2v p3 = __builtin_amdgcn_cvt_pkrtz((XB).z, (XB).w);            \
            B1[4] = p2[0]; B1[5] = p2[1]; B1[6] = p3[0]; B1[7] = p3[1];        \
        } else if (g == 1) {                                                   \
            B1[4] = (__fp16)1.0f;  /* k==20 -> constant-1 bias column */       \
            B1[5] = (__fp16)0.f; B1[6] = (__fp16)0.f; B1[7] = (__fp16)0.f;     \
        } else {                                                               \
            B1[4] = (__fp16)0.f; B1[5] = (__fp16)0.f;                          \
            B1[6] = (__fp16)0.f; B1[7] = (__fp16)0.f;                          \
        }                                                                      \
        f32x4 c0 = MFMA16(A10, B1, zero);                                      \
        f32x4 c1 = MFMA16(A11, B1, zero);                                      \
        half8 B2;                                                              \
        half2v q0 = __builtin_amdgcn_cvt_pkrtz(fmaxf(c0[0],0.f), fmaxf(c0[1],0.f)); \
        half2v q1 = __builtin_amdgcn_cvt_pkrtz(fmaxf(c0[2],0.f), fmaxf(c0[3],0.f)); \
        half2v q2 = __builtin_amdgcn_cvt_pkrtz(fmaxf(c1[0],0.f), fmaxf(c1[1],0.f)); \
        half2v q3 = __builtin_amdgcn_cvt_pkrtz(fmaxf(c1[2],0.f), fmaxf(c1[3],0.f)); \
        B2[0] = q0[0]; B2[1] = q0[1]; B2[2] = q1[0]; B2[3] = q1[1];            \
        B2[4] = q2[0]; B2[5] = q2[1]; B2[6] = q3[0]; B2[7] = q3[1];            \
        if (g == 1) B2[4] = (__fp16)1.0f;  /* m==20 -> h2_ext bias row */      \
        f32x4 d0 = MFMA16(A20, B2, zero);                                      \
        f32x4 d1 = MFMA16(A21, B2, zero);                                      \
        if (LIVE) {                                                            \
            _Pragma("unroll")                                                  \
            for (int q = 0; q < 4; ++q) {                                      \
                psum += d0[q]; pabs += fabsf(d0[q]);                           \
                psum += d1[q]; pabs += fabsf(d1[q]);                           \
            }                                                                  \
        }                                                                      \
    }

// ---------------------------------------------------------------------------
// Setup (1 block): build the four f16 MFMA A-fragments (16x16x32 layout).
//   f=0,1: GEMM1 A = At_ext, row m=(f&1)*16+(l&15), k=i
//          At[m][i] = sum_j W[j,i]R[j,m] (i<20); i==20 -> 1 + sum_j b_j R[j,m]
//   f=2,3: GEMM2 A = W_ext, row n=(f&1)*16+(l&15), k=m; m==20 -> b[n]
//   k(e) = e<4 ? 4g+e : 16+4g+(e-4), g=(l>>4)
// ---------------------------------------------------------------------------
__global__ void mlp_setup(const float* __restrict__ W, const float* __restrict__ b,
                          const float* __restrict__ R, __fp16* __restrict__ frag) {
    int t = threadIdx.x;                 // t = f*64 + l
    int f = t >> 6, l = t & 63;
    int g = l >> 4, p = l & 15;
    int row = (f & 1) * 16 + p;
    #pragma unroll
    for (int e = 0; e < 8; ++e) {
        int k = (e < 4) ? (4 * g + e) : (16 + 4 * g + (e - 4));
        float v = 0.f;
        if (f < 2) {                     // GEMM1 weights
            if (row < FF) {
                if (k < FF) {
                    float s = 0.f;
                    for (int j = 0; j < FF; ++j) s = fmaf(W[j * FF + k], R[j * FF + row], s);
                    v = s;
                } else if (k == FF) {
                    float s = 1.0f;
                    for (int j = 0; j < FF; ++j) s = fmaf(b[j], R[j * FF + row], s);
                    v = s;
                }
            }
        } else {                         // GEMM2 weights
            if (row < FF) {
                if (k < FF) v = W[row * FF + k];
                else if (k == FF) v = b[row];
            }
        }
        frag[t * 8 + e] = (__fp16)v;
    }
}

// ---------------------------------------------------------------------------
// Main: per wave, DMA the wave's 10240B x-slab into LDS with 10 DENSE
// global_load_lds_dwordx4 (lane i -> byte i*16; wave-uniform LDS base; no
// VGPR round-trip), s_waitcnt vmcnt(0) (wave-private region, no barrier),
// then per tile read B1 fragments from LDS (2x ds_read_b128, ~2-way bank
// aliasing = free) -> 2 MFMA -> relu/pack -> 2 MFMA -> sum/|sum|.
// Replaces R8's 16 strided float4 loads/wave (~20 cachelines per VMEM op,
// 5x request fragmentation) with 10 dense ops (4 cachelines each).
// ---------------------------------------------------------------------------
__global__ __launch_bounds__(TPB) void mlp_main(
    const float* __restrict__ x, const __fp16* __restrict__ frag,
    double2* __restrict__ partials, int nrows)
{
    __shared__ char stage[(TPB / 64) * WAVE_BYTES] __attribute__((aligned(16)));
    const int t = threadIdx.x;
    const int l = t & 63;
    const int g = l >> 4;        // 0..3 (k-chunk)
    const int r = l & 15;        // row within tile == output col
    const int wid = t >> 6;

    // persistent A-fragments (16 VGPRs)
    const half8 A10 = *reinterpret_cast<const half8*>(frag + (0 * 64 + l) * 8);
    const half8 A11 = *reinterpret_cast<const half8*>(frag + (1 * 64 + l) * 8);
    const half8 A20 = *reinterpret_cast<const half8*>(frag + (2 * 64 + l) * 8);
    const half8 A21 = *reinterpret_cast<const half8*>(frag + (3 * 64 + l) * 8);

    const int wave_id = blockIdx.x * (TPB / 64) + wid;
    const long wave_byte0 = (long)wave_id * WAVE_BYTES;
    const long max_byte = (long)nrows * (FF * 4) - 16;
    char* lbase = stage + wid * WAVE_BYTES;

    // ---- dense DMA stage: 10 global_load_lds_dwordx4, all in flight ----
    #pragma unroll
    for (int v = 0; v < DMA_N; ++v) {
        long gb = wave_byte0 + (long)v * 1024 + (long)l * 16;
        if (gb > max_byte) gb = max_byte;          // clamp (no-op at N=1M)
        const void* gp = (const char*)x + gb;
        __builtin_amdgcn_global_load_lds(
            (const __attribute__((address_space(1))) unsigned int*)gp,
            (__attribute__((address_space(3))) unsigned int*)(lbase + v * 1024),
            16, 0, 0);
    }
    asm volatile("s_waitcnt vmcnt(0)" ::: "memory");

    // ---- compute 8 tiles from LDS ----
    float psum = 0.f, pabs = 0.f;
    const f32x4 zero = {0.f, 0.f, 0.f, 0.f};
    const long row0 = (long)wave_id * (TPW * 16) + r;
    #pragma unroll
    for (int u = 0; u < TPW; ++u) {
        const float4 xA = *reinterpret_cast<const float4*>(
            lbase + u * TILE_BYTES + r * 80 + g * 16);
        float4 xB = make_float4(0.f, 0.f, 0.f, 0.f);
        if (g == 0)
            xB = *reinterpret_cast<const float4*>(
                lbase + u * TILE_BYTES + r * 80 + 64);
        TILE_BODY(xA, xB, (row0 + u * 16 < nrows));
    }

    // ---- wave + block reduction -> one double2 per block ----
    #pragma unroll
    for (int off = 32; off > 0; off >>= 1) {
        psum += __shfl_down(psum, off, 64);
        pabs += __shfl_down(pabs, off, 64);
    }
    __shared__ double wsum[TPB / 64], wabs[TPB / 64];
    if ((t & 63) == 0) { wsum[wid] = (double)psum; wabs[wid] = (double)pabs; }
    __syncthreads();
    if (t == 0) {
        double bs = 0.0, ba = 0.0;
        #pragma unroll
        for (int w = 0; w < TPB / 64; ++w) { bs += wsum[w]; ba += wabs[w]; }
        partials[blockIdx.x] = make_double2(bs, ba);
    }
}

// ---------------------------------------------------------------------------
// Final: deterministic tree-reduce of block partials; halving count; output.
// ---------------------------------------------------------------------------
__global__ __launch_bounds__(256) void mlp_final(const double2* __restrict__ parts,
                                                 int nparts, float* __restrict__ out) {
    __shared__ double s_sum[256], s_abs[256];
    int t = threadIdx.x;
    double a = 0.0, sg = 0.0;
    for (int i = t; i < nparts; i += 256) { sg += parts[i].x; a += parts[i].y; }
    s_sum[t] = sg; s_abs[t] = a;
    __syncthreads();
    for (int off = 128; off > 0; off >>= 1) {
        if (t < off) { s_sum[t] += s_sum[t + off]; s_abs[t] += s_abs[t + off]; }
        __syncthreads();
    }
    if (t == 0) {
        double s = s_abs[0];
        int k = 0;
        while (s > 1.0 && k < 4000) { s *= 0.5; ++k; }
        out[0] = (float)ldexp(s_sum[0], -k);
    }
}

extern "C" void kernel_launch(void* const* d_in, const int* in_sizes, int n_in,
                              void* d_out, int out_size, void* d_ws, size_t ws_size,
                              hipStream_t stream) {
    const float* x = (const float*)d_in[0];
    const float* W = (const float*)d_in[1];
    const float* b = (const float*)d_in[2];
    const float* R = (const float*)d_in[3];
    float* out = (float*)d_out;

    // d_ws: [0,4KB) A-fragments (4*64*8 f16), [8KB, ...) double2 partials
    __fp16* frag = (__fp16*)d_ws;
    double2* partials = (double2*)((char*)d_ws + 8192);

    int nrows = in_sizes[0] / FF;
    int ntiles = (nrows + 15) / 16;
    int waves = (ntiles + TPW - 1) / TPW;
    int blocks = (waves + (TPB / 64) - 1) / (TPB / 64);

    hipLaunchKernelGGL(mlp_setup, dim3(1), dim3(256), 0, stream, W, b, R, frag);
    hipLaunchKernelGGL(mlp_main, dim3(blocks), dim3(TPB), 0, stream,
                       x, frag, partials, nrows);
    hipLaunchKernelGGL(mlp_final, dim3(1), dim3(256), 0, stream, partials, blocks, out);
}